// Round 7
// baseline (357.167 us; speedup 1.0000x reference)
//
#include <hip/hip_runtime.h>
#include <stdint.h>

#define NH 16
#define HD 64
#define SQ 1024
#define SK 4096
#define DM 1024
#define MQ 2048      // B*Sq
#define MK 8192      // B*Sk
#define MTOT 18432   // MQ + MK + MK

typedef short s16x8 __attribute__((ext_vector_type(8)));
typedef short s16x4 __attribute__((ext_vector_type(4)));
typedef float f32x4 __attribute__((ext_vector_type(4)));

// async global->LDS DMA, 16B per lane; LDS dest must be wave-uniform-base + lane*16
#define GLOAD_LDS16(g, l) __builtin_amdgcn_global_load_lds( \
    (const __attribute__((address_space(1))) void*)(g), \
    (__attribute__((address_space(3))) void*)(l), 16, 0, 0)

__device__ __forceinline__ short f2bf(float f) {   // RNE
  union { float f; uint32_t u; } v; v.f = f;
  uint32_t r = (v.u + 0x7FFFu + ((v.u >> 16) & 1u)) >> 16;
  return (short)(uint16_t)r;
}
__device__ __forceinline__ short f2bf_rz(float f) { // truncate (P values >= 0)
  union { float f; uint32_t u; } v; v.f = f;
  return (short)(uint16_t)(v.u >> 16);
}

// ---------------- fp32 -> bf16 convert (vectorized x8) ----------------
__global__ void cvt_kernel(const float* __restrict__ src, short* __restrict__ dst, int n8) {
  int stride = gridDim.x * blockDim.x;
  for (int i = blockIdx.x * blockDim.x + threadIdx.x; i < n8; i += stride) {
    const float4* s4 = (const float4*)src + 2 * (size_t)i;
    float4 a = s4[0], b = s4[1];
    s16x8 o;
    o[0] = f2bf(a.x); o[1] = f2bf(a.y); o[2] = f2bf(a.z); o[3] = f2bf(a.w);
    o[4] = f2bf(b.x); o[5] = f2bf(b.y); o[6] = f2bf(b.z); o[7] = f2bf(b.w);
    *((s16x8*)dst + i) = o;
  }
}

// ---------------- mask -> additive bias (exp2 domain, fixed shift -8) ----------------
__global__ void maskf_kernel(const int* __restrict__ km, float* __restrict__ madd_g) {
  int i = blockIdx.x * 256 + threadIdx.x;
  if (i < 2 * SK) madd_g[i] = km[i] ? -8.0f : -1e9f;
}

// ---------------- weight transpose + convert: W[K][N] f32 -> Wt[N][K] bf16 ----------------
__global__ void twkernel(const float* __restrict__ W, short* __restrict__ Wt) {
  __shared__ __align__(16) short t[64][65];
  int lx = threadIdx.x & 63, ly = threadIdx.x >> 6;
  int c0 = (blockIdx.x & 15) * 64, r0 = (blockIdx.x >> 4) * 64;
  #pragma unroll
  for (int i = ly; i < 64; i += 4) t[i][lx] = f2bf(W[(size_t)(r0 + i) * DM + c0 + lx]);
  __syncthreads();
  #pragma unroll
  for (int i = ly; i < 64; i += 4) Wt[(size_t)(c0 + i) * DM + r0 + lx] = t[lx][i];
}

// ---------------- fused QKV projection GEMM (BK=64) ----------------
__global__ __launch_bounds__(256) void proj_gemm(
    const short* __restrict__ Acat,
    const short* __restrict__ Wqt, const short* __restrict__ Wkt, const short* __restrict__ Wvt,
    const float* __restrict__ bq, const float* __restrict__ bk, const float* __restrict__ bv,
    short* __restrict__ Qp, short* __restrict__ Kp, short* __restrict__ Vp)
{
  __shared__ __align__(16) short As[128 * 64];
  __shared__ __align__(16) short Bs[128 * 64];
  int tid = threadIdx.x, lane = tid & 63, wid = tid >> 6;
  int bm = blockIdx.x >> 3, bn = blockIdx.x & 7;
  int m0 = bm * 128, n0 = bn * 128;
  int seg = (m0 < MQ) ? 0 : (m0 < MQ + MK) ? 1 : 2;
  const short* Wt = (seg == 0) ? Wqt : (seg == 1) ? Wkt : Wvt;
  const float* bias = (seg == 0) ? bq : (seg == 1) ? bk : bv;

  int rs = tid >> 3;               // 0..31 (staging row)
  int cb8 = (tid & 7) * 8;         // staging k-col (elems)
  int wr = wid >> 1, wc = wid & 1;
  int l15 = lane & 15, g = lane >> 4;

  f32x4 acc[4][4] = {};

  const short* gA = Acat + (size_t)(m0 + rs) * DM + cb8;
  const short* gB = Wt + (size_t)(n0 + rs) * DM + cb8;
  char* lA = (char*)As + tid * 16;
  char* lB = (char*)Bs + tid * 16;

  for (int kt = 0; kt < 16; ++kt) {
    int k0 = kt * 64;
    __syncthreads();
    GLOAD_LDS16(gA + k0,            lA);
    GLOAD_LDS16(gA + 32 * DM + k0,  lA + 4096);
    GLOAD_LDS16(gA + 64 * DM + k0,  lA + 8192);
    GLOAD_LDS16(gA + 96 * DM + k0,  lA + 12288);
    GLOAD_LDS16(gB + k0,            lB);
    GLOAD_LDS16(gB + 32 * DM + k0,  lB + 4096);
    GLOAD_LDS16(gB + 64 * DM + k0,  lB + 8192);
    GLOAD_LDS16(gB + 96 * DM + k0,  lB + 12288);
    __syncthreads();
    #pragma unroll
    for (int kk = 0; kk < 2; ++kk) {
      s16x8 af[4], bfr[4];
      #pragma unroll
      for (int mi = 0; mi < 4; ++mi)
        af[mi] = *(const s16x8*)((const char*)As + (wr * 64 + mi * 16 + l15) * 128 + kk * 64 + g * 16);
      #pragma unroll
      for (int ni = 0; ni < 4; ++ni)
        bfr[ni] = *(const s16x8*)((const char*)Bs + (wc * 64 + ni * 16 + l15) * 128 + kk * 64 + g * 16);
      #pragma unroll
      for (int mi = 0; mi < 4; ++mi)
        #pragma unroll
        for (int ni = 0; ni < 4; ++ni)
          acc[mi][ni] = __builtin_amdgcn_mfma_f32_16x16x32_bf16(af[mi], bfr[ni], acc[mi][ni], 0, 0, 0);
    }
  }

  __syncthreads();   // epilogue reuses As as scratch

  if (seg == 2) {
    short* tw = (short*)As + wid * 288;   // [16][18] per wave
    int vbase = m0 - (MQ + MK) + wr * 64;
    #pragma unroll
    for (int mi = 0; mi < 4; ++mi) {
      int vr = vbase + mi * 16 + l15;
      int bb2 = vr >> 12, sk = vr & 4095;
      #pragma unroll
      for (int ni = 0; ni < 4; ++ni) {
        int col = n0 + wc * 64 + ni * 16;
        int h = col >> 6, d0 = col & 63;
        float bb = bias[col + l15];
        #pragma unroll
        for (int r = 0; r < 4; ++r)
          tw[(g * 4 + r) * 18 + l15] = f2bf(acc[mi][ni][r] + bb);
        #pragma unroll
        for (int j = 0; j < 4; ++j) {
          int dl = g * 4 + j;
          Vp[((size_t)(bb2 * NH + h) * HD + d0 + dl) * SK + sk] = tw[l15 * 18 + dl];
        }
      }
    }
  } else {
    // per-wave [16][64] shorts (2KB), XOR-swizzled; 16B coalesced global stores
    char* tw2 = (char*)As + wid * 2048;
    int hh = (n0 + wc * 64) >> 6;
    short* outp = (seg == 0) ? Qp : Kp;
    int sdim = (seg == 0) ? SQ : SK;
    int rbase = (seg == 0) ? m0 : m0 - MQ;
    int rmask = (seg == 0) ? 1023 : 4095;
    int rshift = (seg == 0) ? 10 : 12;
    #pragma unroll
    for (int mi = 0; mi < 4; ++mi) {
      #pragma unroll
      for (int ni = 0; ni < 4; ++ni) {
        float bb = bias[n0 + wc * 64 + ni * 16 + l15];
        #pragma unroll
        for (int r = 0; r < 4; ++r) {
          int rw = g * 4 + r;
          *(short*)(tw2 + rw * 128 + (((ni * 16 + l15) * 2) ^ ((rw & 7) << 4))) =
              f2bf(acc[mi][ni][r] + bb);
        }
      }
      asm volatile("s_waitcnt lgkmcnt(0)" ::: "memory");
      #pragma unroll
      for (int pp = 0; pp < 2; ++pp) {
        int lr = pp * 8 + (lane >> 3);
        int ce = (lane & 7) * 8;
        s16x8 v8 = *(const s16x8*)(tw2 + lr * 128 + ((ce * 2) ^ ((lr & 7) << 4)));
        int row = rbase + wr * 64 + mi * 16 + lr;
        int bI = row >> rshift, s = row & rmask;
        *(s16x8*)(outp + ((size_t)(bI * NH + hh) * sdim + s) * HD + ce) = v8;
      }
      asm volatile("s_waitcnt lgkmcnt(0)" ::: "memory");
    }
  }
}

// ---------------- flash attention, KV-split x2 ----------------
// grid 1024: bid = qt*64 + bh*2 + half. Fixed-shift softmax (exp2 dom, shift -8) makes
// partials over disjoint KV ranges purely ADDITIVE: o=o1+o2, l=l1+l2 (no max tracking).
// madd from global (L1-resident); LDS 40KB -> 4 blocks/CU.
__global__ __launch_bounds__(256) void attn_kernel(
    const short* __restrict__ Qp, const short* __restrict__ Kp, const short* __restrict__ Vp,
    const float* __restrict__ madd_g, float* __restrict__ po, float* __restrict__ pl)
{
  __shared__ __align__(16) short Ks[2][64 * 64];   // [sk][d] swizzled, dbuf
  __shared__ __align__(16) short Vs[2][64 * 64];   // [d][sk] swizzled, dbuf
  __shared__ __align__(16) short Ps[4][16 * 64];   // per-wave [q][k] swizzled

  int tid = threadIdx.x, lane = tid & 63, wid = tid >> 6;
  int sub = blockIdx.x & 63, qt = blockIdx.x >> 6;
  int bh = sub >> 1, half = sub & 1;
  int b = bh >> 4;
  const short* Qb = Qp + (size_t)bh * SQ * HD;
  const short* Kb = Kp + (size_t)bh * SK * HD + (size_t)half * 2048 * HD;
  const short* Vb = Vp + (size_t)bh * HD * SK + half * 2048;
  const float* mab = madd_g + b * SK + half * 2048;

  int l15 = lane & 15, g = lane >> 4, lh8 = g * 8;
  int q0 = qt * 64 + wid * 16;
  int swz = (l15 & 7) << 4;

  s16x8 aq[2];
  aq[0] = *(const s16x8*)(Qb + (size_t)(q0 + l15) * HD + lh8);
  aq[1] = *(const s16x8*)(Qb + (size_t)(q0 + l15) * HD + 32 + lh8);

  s16x8 ones;
  #pragma unroll
  for (int j = 0; j < 8; ++j) ones[j] = (short)0x3F80;  // bf16 1.0

  f32x4 o[4] = {};
  f32x4 ol = {};                      // row-sum accumulator (l) via ones-MFMA

  int srow = tid >> 3, scEl = (tid & 7) * 8;
  int wsoff = srow * 128 + ((scEl * 2) ^ ((srow & 7) << 4));  // swizzled byte offset

  s16x8 rk0, rk1, rv0, rv1;
#define ALOADS(t) { \
    rk0 = *(const s16x8*)(Kb + (size_t)((t) * 64 + srow) * HD + scEl); \
    rk1 = *(const s16x8*)(Kb + (size_t)((t) * 64 + srow + 32) * HD + scEl); \
    rv0 = *(const s16x8*)(Vb + (size_t)srow * SK + (t) * 64 + scEl); \
    rv1 = *(const s16x8*)(Vb + (size_t)(srow + 32) * SK + (t) * 64 + scEl); }
#define STAGE(bi) { \
    char* kb_ = (char*)Ks[bi]; char* vb_ = (char*)Vs[bi]; \
    *(s16x8*)(kb_ + wsoff) = rk0; *(s16x8*)(kb_ + wsoff + 4096) = rk1; \
    *(s16x8*)(vb_ + wsoff) = rv0; *(s16x8*)(vb_ + wsoff + 4096) = rv1; }

  ALOADS(0); STAGE(0); ALOADS(1);
  __syncthreads();                    // buf0 visible

  const float sscale = 0.18033688f;   // 0.125 * log2(e)
  for (int t = 0; t < 32; ++t) {
    int cur = t & 1;
    if (t < 31) STAGE(cur ^ 1);
    if (t < 30) ALOADS(t + 2);
    const char* KsB = (const char*)Ks[cur];
    const char* VsB = (const char*)Vs[cur];

    // S = Q K^T  (16 q-rows x 64 sk-cols)
    f32x4 sc[4] = {};
    __builtin_amdgcn_s_setprio(1);
    #pragma unroll
    for (int ni = 0; ni < 4; ++ni) {
      #pragma unroll
      for (int ks = 0; ks < 2; ++ks) {
        s16x8 kf = *(const s16x8*)(KsB + (ni * 16 + l15) * 128 + ((ks * 64 + g * 16) ^ swz));
        sc[ni] = __builtin_amdgcn_mfma_f32_16x16x32_bf16(aq[ks], kf, sc[ni], 0, 0, 0);
      }
    }
    __builtin_amdgcn_s_setprio(0);

    // P = exp2(S*sscale + madd) -> LDS (swizzled, wave-private)
    char* PsW = (char*)&Ps[wid][0];
    #pragma unroll
    for (int ni = 0; ni < 4; ++ni) {
      float ma = mab[t * 64 + ni * 16 + l15];
      #pragma unroll
      for (int r = 0; r < 4; ++r) {
        float p = exp2f(sc[ni][r] * sscale + ma);
        int prow = g * 4 + r;
        *(short*)(PsW + prow * 128 + (((ni * 16 + l15) * 2) ^ ((prow & 7) << 4))) = f2bf_rz(p);
      }
    }
    asm volatile("s_waitcnt lgkmcnt(0)" ::: "memory");

    // PV + l accumulation (ones-matrix MFMA)
    __builtin_amdgcn_s_setprio(1);
    #pragma unroll
    for (int ks2 = 0; ks2 < 2; ++ks2) {
      s16x8 pa = *(const s16x8*)(PsW + l15 * 128 + ((ks2 * 64 + g * 16) ^ swz));
      #pragma unroll
      for (int nd = 0; nd < 4; ++nd) {
        s16x8 vf = *(const s16x8*)(VsB + (nd * 16 + l15) * 128 + ((ks2 * 64 + g * 16) ^ swz));
        o[nd] = __builtin_amdgcn_mfma_f32_16x16x32_bf16(pa, vf, o[nd], 0, 0, 0);
      }
      ol = __builtin_amdgcn_mfma_f32_16x16x32_bf16(pa, ones, ol, 0, 0, 0);
    }
    __builtin_amdgcn_s_setprio(0);
    __syncthreads();
  }
#undef ALOADS
#undef STAGE

  // write partials: po[bid][ql][d], pl[bid][ql]
  float* poB = po + (size_t)blockIdx.x * 4096;
  #pragma unroll
  for (int nd = 0; nd < 4; ++nd) {
    #pragma unroll
    for (int r = 0; r < 4; ++r) {
      int ql = wid * 16 + g * 4 + r;
      poB[ql * 64 + nd * 16 + l15] = o[nd][r];
    }
  }
  if (l15 == 0) {
    #pragma unroll
    for (int r = 0; r < 4; ++r)
      pl[(size_t)blockIdx.x * 64 + wid * 16 + g * 4 + r] = ol[r];
  }
}

// ---------------- combine partials: ctx = (o1+o2)/(l1+l2) ----------------
__global__ __launch_bounds__(256) void combine_kernel(
    const float* __restrict__ po, const float* __restrict__ pl, short* __restrict__ ctx)
{
  int tg = blockIdx.x * 256 + threadIdx.x;       // 0..524287
  int d4 = (tg & 15) * 4;
  int idx = tg >> 4;                              // 0..32767
  int bh = idx >> 10, qrow = idx & 1023;
  int qt = qrow >> 6, ql = qrow & 63;
  int pid0 = qt * 64 + bh * 2;
  const float4 a = *(const float4*)(po + (size_t)pid0 * 4096 + ql * 64 + d4);
  const float4 c = *(const float4*)(po + (size_t)(pid0 + 1) * 4096 + ql * 64 + d4);
  float rl = 1.0f / (pl[(size_t)pid0 * 64 + ql] + pl[(size_t)(pid0 + 1) * 64 + ql]);
  s16x4 outv;
  outv[0] = f2bf((a.x + c.x) * rl);
  outv[1] = f2bf((a.y + c.y) * rl);
  outv[2] = f2bf((a.z + c.z) * rl);
  outv[3] = f2bf((a.w + c.w) * rl);
  int b = bh >> 4, h = bh & 15;
  *(s16x4*)(ctx + ((size_t)(b * SQ + qrow)) * DM + h * HD + d4) = outv;
}

// ---------------- output projection GEMM (BK=64): out = ctx @ Wo + bo (fp32) ----------------
__global__ __launch_bounds__(256) void out_gemm(
    const short* __restrict__ Actx, const short* __restrict__ Wot,
    const float* __restrict__ bo, float* __restrict__ out)
{
  __shared__ __align__(16) short As[128 * 64];
  __shared__ __align__(16) short Bs[128 * 64];
  int tid = threadIdx.x, lane = tid & 63, wid = tid >> 6;
  int bm = blockIdx.x >> 3, bn = blockIdx.x & 7;
  int m0 = bm * 128, n0 = bn * 128;

  int rs = tid >> 3;
  int cb8 = (tid & 7) * 8;
  int wr = wid >> 1, wc = wid & 1;
  int l15 = lane & 15, g = lane >> 4;

  f32x4 acc[4][4] = {};

  const short* gA = Actx + (size_t)(m0 + rs) * DM + cb8;
  const short* gB = Wot + (size_t)(n0 + rs) * DM + cb8;
  char* lA = (char*)As + tid * 16;
  char* lB = (char*)Bs + tid * 16;

  for (int kt = 0; kt < 16; ++kt) {
    int k0 = kt * 64;
    __syncthreads();
    GLOAD_LDS16(gA + k0,            lA);
    GLOAD_LDS16(gA + 32 * DM + k0,  lA + 4096);
    GLOAD_LDS16(gA + 64 * DM + k0,  lA + 8192);
    GLOAD_LDS16(gA + 96 * DM + k0,  lA + 12288);
    GLOAD_LDS16(gB + k0,            lB);
    GLOAD_LDS16(gB + 32 * DM + k0,  lB + 4096);
    GLOAD_LDS16(gB + 64 * DM + k0,  lB + 8192);
    GLOAD_LDS16(gB + 96 * DM + k0,  lB + 12288);
    __syncthreads();
    #pragma unroll
    for (int kk = 0; kk < 2; ++kk) {
      s16x8 af[4], bfr[4];
      #pragma unroll
      for (int mi = 0; mi < 4; ++mi)
        af[mi] = *(const s16x8*)((const char*)As + (wr * 64 + mi * 16 + l15) * 128 + kk * 64 + g * 16);
      #pragma unroll
      for (int ni = 0; ni < 4; ++ni)
        bfr[ni] = *(const s16x8*)((const char*)Bs + (wc * 64 + ni * 16 + l15) * 128 + kk * 64 + g * 16);
      #pragma unroll
      for (int mi = 0; mi < 4; ++mi)
        #pragma unroll
        for (int ni = 0; ni < 4; ++ni)
          acc[mi][ni] = __builtin_amdgcn_mfma_f32_16x16x32_bf16(af[mi], bfr[ni], acc[mi][ni], 0, 0, 0);
    }
  }

  #pragma unroll
  for (int mi = 0; mi < 4; ++mi) {
    #pragma unroll
    for (int ni = 0; ni < 4; ++ni) {
      int col = n0 + wc * 64 + ni * 16 + l15;
      float bb = bo[col];
      #pragma unroll
      for (int r = 0; r < 4; ++r) {
        int row = m0 + wr * 64 + mi * 16 + g * 4 + r;
        out[(size_t)row * DM + col] = acc[mi][ni][r] + bb;
      }
    }
  }
}

extern "C" void kernel_launch(void* const* d_in, const int* in_sizes, int n_in,
                              void* d_out, int out_size, void* d_ws, size_t ws_size,
                              hipStream_t stream) {
  const float* query = (const float*)d_in[0];
  const float* key   = (const float*)d_in[1];
  const float* value = (const float*)d_in[2];
  const int*   kmask = (const int*)d_in[3];
  const float* Wq = (const float*)d_in[4];
  const float* bq = (const float*)d_in[5];
  const float* Wk = (const float*)d_in[6];
  const float* bk = (const float*)d_in[7];
  const float* Wv = (const float*)d_in[8];
  const float* bv = (const float*)d_in[9];
  const float* Wo = (const float*)d_in[10];
  const float* bo = (const float*)d_in[11];
  float* out = (float*)d_out;

  char* ws = (char*)d_ws;
  short* Acat = (short*)ws;                       // 18432*1024 bf16 = 36 MB
  short* Wqt  = (short*)(ws + (size_t)37748736);  // 4 x 2MB
  short* Wkt  = Wqt + 1048576;
  short* Wvt  = Wkt + 1048576;
  short* Wot  = Wvt + 1048576;
  short* Qp   = Wot + 1048576;                    // [B,H,Sq,64]  4 MB
  short* Kp   = Qp + 2097152;                     // [B,H,Sk,64] 16 MB
  short* Vp   = Kp + 8388608;                     // [B,H,64,Sk] 16 MB
  short* ctx  = Vp + 8388608;                     // [B,Sq,1024]  4 MB
  float* madd_g = (float*)(ctx + 2097152);        // 32 KB

  // partials alias Acat (dead after proj_gemm; stream-ordered)
  float* po = (float*)Acat;                       // 1024*4096 f32 = 16 MB
  float* pl = po + (size_t)1024 * 4096;           // 256 KB

  short* qbf = Acat;
  short* kbf = Acat + 2097152;
  short* vbf = Acat + 2097152 + 8388608;

  cvt_kernel<<<1024, 256, 0, stream>>>(query, qbf, 2097152 / 8);
  cvt_kernel<<<2048, 256, 0, stream>>>(key,   kbf, 8388608 / 8);
  cvt_kernel<<<2048, 256, 0, stream>>>(value, vbf, 8388608 / 8);
  maskf_kernel<<<32, 256, 0, stream>>>(kmask, madd_g);
  twkernel<<<256, 256, 0, stream>>>(Wq, Wqt);
  twkernel<<<256, 256, 0, stream>>>(Wk, Wkt);
  twkernel<<<256, 256, 0, stream>>>(Wv, Wvt);
  twkernel<<<256, 256, 0, stream>>>(Wo, Wot);
  proj_gemm<<<1152, 256, 0, stream>>>(Acat, Wqt, Wkt, Wvt, bq, bk, bv, Qp, Kp, Vp);
  attn_kernel<<<1024, 256, 0, stream>>>(Qp, Kp, Vp, madd_g, po, pl);
  combine_kernel<<<2048, 256, 0, stream>>>(po, pl, ctx);
  out_gemm<<<128, 256, 0, stream>>>(ctx, Wot, bo, out);
}

// Round 8
// 325.378 us; speedup vs baseline: 1.0977x; 1.0977x over previous
//
#include <hip/hip_runtime.h>
#include <stdint.h>

#define NH 16
#define HD 64
#define SQ 1024
#define SK 4096
#define DM 1024
#define MQ 2048      // B*Sq
#define MK 8192      // B*Sk
#define MTOT 18432   // MQ + MK + MK

typedef short s16x8 __attribute__((ext_vector_type(8)));
typedef short s16x4 __attribute__((ext_vector_type(4)));
typedef float f32x4 __attribute__((ext_vector_type(4)));

// async global->LDS DMA, 16B per lane; LDS dest must be wave-uniform-base + lane*16
#define GLOAD_LDS16(g, l) __builtin_amdgcn_global_load_lds( \
    (const __attribute__((address_space(1))) void*)(g), \
    (__attribute__((address_space(3))) void*)(l), 16, 0, 0)

__device__ __forceinline__ short f2bf(float f) {   // RNE
  union { float f; uint32_t u; } v; v.f = f;
  uint32_t r = (v.u + 0x7FFFu + ((v.u >> 16) & 1u)) >> 16;
  return (short)(uint16_t)r;
}
__device__ __forceinline__ short f2bf_rz(float f) { // truncate (P values >= 0)
  union { float f; uint32_t u; } v; v.f = f;
  return (short)(uint16_t)(v.u >> 16);
}

// ---------------- prep: fp32->bf16 for q/k/v + mask bitpack ----------------
__global__ void prep_kernel(const float* __restrict__ q, const float* __restrict__ k,
                            const float* __restrict__ v, const int* __restrict__ km,
                            short* __restrict__ qbf, short* __restrict__ kbf,
                            short* __restrict__ vbf, uint32_t* __restrict__ mbits) {
  int gid = blockIdx.x * 256 + threadIdx.x;
  if (gid < 256) {                         // 2*4096 mask bits -> 256 u32 words
    const int* kmw = km + gid * 32;
    uint32_t bits = 0;
    #pragma unroll
    for (int j = 0; j < 32; ++j) bits |= (kmw[j] ? 1u : 0u) << j;
    mbits[gid] = bits;
  }
  int stride = gridDim.x * 256;
  for (int i = gid; i < 2359296; i += stride) {   // total (2048+8192+8192)*1024/8
    const float* src; short* dst; int off;
    if (i < 262144)       { src = q; dst = qbf; off = i; }
    else if (i < 1310720) { src = k; dst = kbf; off = i - 262144; }
    else                  { src = v; dst = vbf; off = i - 1310720; }
    const float4* s4 = (const float4*)src + 2 * (size_t)off;
    float4 a = s4[0], b = s4[1];
    s16x8 o;
    o[0] = f2bf(a.x); o[1] = f2bf(a.y); o[2] = f2bf(a.z); o[3] = f2bf(a.w);
    o[4] = f2bf(b.x); o[5] = f2bf(b.y); o[6] = f2bf(b.z); o[7] = f2bf(b.w);
    *((s16x8*)dst + off) = o;
  }
}

// ---------------- weight transpose + convert, all 4 weights: W[K][N] f32 -> Wt[N][K] bf16 ----------------
__global__ void twall_kernel(const float* __restrict__ Wq, const float* __restrict__ Wk,
                             const float* __restrict__ Wv, const float* __restrict__ Wo,
                             short* __restrict__ Wqt, short* __restrict__ Wkt,
                             short* __restrict__ Wvt, short* __restrict__ Wot) {
  __shared__ __align__(16) short t[64][65];
  int wsel = blockIdx.x >> 8, bid = blockIdx.x & 255;
  const float* W = (wsel == 0) ? Wq : (wsel == 1) ? Wk : (wsel == 2) ? Wv : Wo;
  short* Wt = (wsel == 0) ? Wqt : (wsel == 1) ? Wkt : (wsel == 2) ? Wvt : Wot;
  int lx = threadIdx.x & 63, ly = threadIdx.x >> 6;
  int c0 = (bid & 15) * 64, r0 = (bid >> 4) * 64;
  #pragma unroll
  for (int i = ly; i < 64; i += 4) t[i][lx] = f2bf(W[(size_t)(r0 + i) * DM + c0 + lx]);
  __syncthreads();
  #pragma unroll
  for (int i = ly; i < 64; i += 4) Wt[(size_t)(c0 + i) * DM + r0 + lx] = t[lx][i];
}

// ---------------- fused QKV projection GEMM (BK=64) ----------------
__global__ __launch_bounds__(256) void proj_gemm(
    const short* __restrict__ Acat,
    const short* __restrict__ Wqt, const short* __restrict__ Wkt, const short* __restrict__ Wvt,
    const float* __restrict__ bq, const float* __restrict__ bk, const float* __restrict__ bv,
    short* __restrict__ Qp, short* __restrict__ Kp, short* __restrict__ Vp)
{
  __shared__ __align__(16) short As[128 * 64];
  __shared__ __align__(16) short Bs[128 * 64];
  int tid = threadIdx.x, lane = tid & 63, wid = tid >> 6;
  int bm = blockIdx.x >> 3, bn = blockIdx.x & 7;
  int m0 = bm * 128, n0 = bn * 128;
  int seg = (m0 < MQ) ? 0 : (m0 < MQ + MK) ? 1 : 2;
  const short* Wt = (seg == 0) ? Wqt : (seg == 1) ? Wkt : Wvt;
  const float* bias = (seg == 0) ? bq : (seg == 1) ? bk : bv;

  int rs = tid >> 3;               // 0..31 (staging row)
  int cb8 = (tid & 7) * 8;         // staging k-col (elems)
  int wr = wid >> 1, wc = wid & 1;
  int l15 = lane & 15, g = lane >> 4;

  f32x4 acc[4][4] = {};

  const short* gA = Acat + (size_t)(m0 + rs) * DM + cb8;
  const short* gB = Wt + (size_t)(n0 + rs) * DM + cb8;
  char* lA = (char*)As + tid * 16;
  char* lB = (char*)Bs + tid * 16;

  for (int kt = 0; kt < 16; ++kt) {
    int k0 = kt * 64;
    __syncthreads();
    GLOAD_LDS16(gA + k0,            lA);
    GLOAD_LDS16(gA + 32 * DM + k0,  lA + 4096);
    GLOAD_LDS16(gA + 64 * DM + k0,  lA + 8192);
    GLOAD_LDS16(gA + 96 * DM + k0,  lA + 12288);
    GLOAD_LDS16(gB + k0,            lB);
    GLOAD_LDS16(gB + 32 * DM + k0,  lB + 4096);
    GLOAD_LDS16(gB + 64 * DM + k0,  lB + 8192);
    GLOAD_LDS16(gB + 96 * DM + k0,  lB + 12288);
    __syncthreads();
    #pragma unroll
    for (int kk = 0; kk < 2; ++kk) {
      s16x8 af[4], bfr[4];
      #pragma unroll
      for (int mi = 0; mi < 4; ++mi)
        af[mi] = *(const s16x8*)((const char*)As + (wr * 64 + mi * 16 + l15) * 128 + kk * 64 + g * 16);
      #pragma unroll
      for (int ni = 0; ni < 4; ++ni)
        bfr[ni] = *(const s16x8*)((const char*)Bs + (wc * 64 + ni * 16 + l15) * 128 + kk * 64 + g * 16);
      #pragma unroll
      for (int mi = 0; mi < 4; ++mi)
        #pragma unroll
        for (int ni = 0; ni < 4; ++ni)
          acc[mi][ni] = __builtin_amdgcn_mfma_f32_16x16x32_bf16(af[mi], bfr[ni], acc[mi][ni], 0, 0, 0);
    }
  }

  __syncthreads();   // epilogue reuses As as scratch

  if (seg == 2) {
    short* tw = (short*)As + wid * 288;   // [16][18] per wave
    int vbase = m0 - (MQ + MK) + wr * 64;
    #pragma unroll
    for (int mi = 0; mi < 4; ++mi) {
      int vr = vbase + mi * 16 + l15;
      int bb2 = vr >> 12, sk = vr & 4095;
      #pragma unroll
      for (int ni = 0; ni < 4; ++ni) {
        int col = n0 + wc * 64 + ni * 16;
        int h = col >> 6, d0 = col & 63;
        float bb = bias[col + l15];
        #pragma unroll
        for (int r = 0; r < 4; ++r)
          tw[(g * 4 + r) * 18 + l15] = f2bf(acc[mi][ni][r] + bb);
        #pragma unroll
        for (int j = 0; j < 4; ++j) {
          int dl = g * 4 + j;
          Vp[((size_t)(bb2 * NH + h) * HD + d0 + dl) * SK + sk] = tw[l15 * 18 + dl];
        }
      }
    }
  } else {
    // per-wave [16][64] shorts (2KB), XOR-swizzled; 16B coalesced global stores
    char* tw2 = (char*)As + wid * 2048;
    int hh = (n0 + wc * 64) >> 6;
    short* outp = (seg == 0) ? Qp : Kp;
    int sdim = (seg == 0) ? SQ : SK;
    int rbase = (seg == 0) ? m0 : m0 - MQ;
    int rmask = (seg == 0) ? 1023 : 4095;
    int rshift = (seg == 0) ? 10 : 12;
    #pragma unroll
    for (int mi = 0; mi < 4; ++mi) {
      #pragma unroll
      for (int ni = 0; ni < 4; ++ni) {
        float bb = bias[n0 + wc * 64 + ni * 16 + l15];
        #pragma unroll
        for (int r = 0; r < 4; ++r) {
          int rw = g * 4 + r;
          *(short*)(tw2 + rw * 128 + (((ni * 16 + l15) * 2) ^ ((rw & 7) << 4))) =
              f2bf(acc[mi][ni][r] + bb);
        }
      }
      asm volatile("s_waitcnt lgkmcnt(0)" ::: "memory");
      #pragma unroll
      for (int pp = 0; pp < 2; ++pp) {
        int lr = pp * 8 + (lane >> 3);
        int ce = (lane & 7) * 8;
        s16x8 v8 = *(const s16x8*)(tw2 + lr * 128 + ((ce * 2) ^ ((lr & 7) << 4)));
        int row = rbase + wr * 64 + mi * 16 + lr;
        int bI = row >> rshift, s = row & rmask;
        *(s16x8*)(outp + ((size_t)(bI * NH + hh) * sdim + s) * HD + ce) = v8;
      }
      asm volatile("s_waitcnt lgkmcnt(0)" ::: "memory");
    }
  }
}

// ---------------- flash attention (single pass, occupancy-tuned) ----------------
// grid 512: bh = bid&31 (XCD locality), qt = bid>>5. KVBLK=64.
// LDS 33.3KB -> 4 blocks/CU: K single-buffered, V double-buffered, mask as bits.
// Fixed-shift exp2 softmax; l via ones-MFMA.
__global__ __launch_bounds__(256) void attn_kernel(
    const short* __restrict__ Qp, const short* __restrict__ Kp, const short* __restrict__ Vp,
    const uint32_t* __restrict__ mbits_g, short* __restrict__ ctx)
{
  __shared__ __align__(16) short Ks[64 * 64];      // [sk][d] swizzled, SINGLE buf (8KB)
  __shared__ __align__(16) short Vs[2][64 * 64];   // [d][sk] swizzled, dbuf (16KB)
  __shared__ __align__(16) short Ps[4][16 * 64];   // per-wave [q][k] swizzled (8KB)
  __shared__ uint32_t mb[128];                     // mask bits for this b (512B)

  int tid = threadIdx.x, lane = tid & 63, wid = tid >> 6;
  int bh = blockIdx.x & 31, qt = blockIdx.x >> 5;
  int b = bh >> 4, h = bh & 15;
  const short* Qb = Qp + (size_t)bh * SQ * HD;
  const short* Kb = Kp + (size_t)bh * SK * HD;
  const short* Vb = Vp + (size_t)bh * HD * SK;

  if (tid < 128) mb[tid] = mbits_g[b * 128 + tid];

  int l15 = lane & 15, g = lane >> 4, lh8 = g * 8;
  int q0 = qt * 64 + wid * 16;
  int swz = (l15 & 7) << 4;

  s16x8 aq[2];
  aq[0] = *(const s16x8*)(Qb + (size_t)(q0 + l15) * HD + lh8);
  aq[1] = *(const s16x8*)(Qb + (size_t)(q0 + l15) * HD + 32 + lh8);

  s16x8 ones;
  #pragma unroll
  for (int j = 0; j < 8; ++j) ones[j] = (short)0x3F80;  // bf16 1.0

  f32x4 o[4] = {};
  f32x4 ol = {};                      // row-sum (l) via ones-MFMA

  int srow = tid >> 3, scEl = (tid & 7) * 8;
  int wsoff = srow * 128 + ((scEl * 2) ^ ((srow & 7) << 4));  // swizzled byte offset

  s16x8 rk0, rk1, rv0, rv1;
#define ALOADS(t) { \
    rk0 = *(const s16x8*)(Kb + (size_t)((t) * 64 + srow) * HD + scEl); \
    rk1 = *(const s16x8*)(Kb + (size_t)((t) * 64 + srow + 32) * HD + scEl); \
    rv0 = *(const s16x8*)(Vb + (size_t)srow * SK + (t) * 64 + scEl); \
    rv1 = *(const s16x8*)(Vb + (size_t)(srow + 32) * SK + (t) * 64 + scEl); }
#define STAGE_K() { \
    *(s16x8*)((char*)Ks + wsoff) = rk0; *(s16x8*)((char*)Ks + wsoff + 4096) = rk1; }
#define STAGE_V(bi) { \
    char* vb_ = (char*)Vs[bi]; \
    *(s16x8*)(vb_ + wsoff) = rv0; *(s16x8*)(vb_ + wsoff + 4096) = rv1; }

  ALOADS(0); STAGE_K(); STAGE_V(0);
  ALOADS(1);
  __syncthreads();                    // K(0), V(0), mb visible

  const float sscale = 0.18033688f;   // 0.125 * log2(e)
  for (int t = 0; t < 64; ++t) {
    int cur = t & 1;
    if (t < 63) STAGE_V(cur ^ 1);     // V(t+1) -> other V buffer (regs from prev ALOADS)

    // S = Q K^T  (reads Ks)
    f32x4 sc[4] = {};
    __builtin_amdgcn_s_setprio(1);
    #pragma unroll
    for (int ni = 0; ni < 4; ++ni) {
      #pragma unroll
      for (int ks = 0; ks < 2; ++ks) {
        s16x8 kf = *(const s16x8*)((const char*)Ks + (ni * 16 + l15) * 128 + ((ks * 64 + g * 16) ^ swz));
        sc[ni] = __builtin_amdgcn_mfma_f32_16x16x32_bf16(aq[ks], kf, sc[ni], 0, 0, 0);
      }
    }
    __builtin_amdgcn_s_setprio(0);
    __syncthreads();                  // barrier A: all waves done reading Ks

    if (t < 63) STAGE_K();            // K(t+1) overwrites Ks, overlaps softmax/PV below
    if (t < 62) ALOADS(t + 2);        // prefetch K/V(t+2); regs free after both stages

    // P = exp2(S*sscale + ma), ma from bitmask: set -> -8 (shift), clear -> -1e9
    uint32_t w0 = mb[2 * t], w1 = mb[2 * t + 1];
    char* PsW = (char*)&Ps[wid][0];
    #pragma unroll
    for (int ni = 0; ni < 4; ++ni) {
      uint32_t w = (ni < 2) ? w0 : w1;
      float ma = ((w >> ((ni & 1) * 16 + l15)) & 1u) ? -8.0f : -1e9f;
      #pragma unroll
      for (int r = 0; r < 4; ++r) {
        float p = exp2f(sc[ni][r] * sscale + ma);
        int prow = g * 4 + r;
        *(short*)(PsW + prow * 128 + (((ni * 16 + l15) * 2) ^ ((prow & 7) << 4))) = f2bf_rz(p);
      }
    }
    asm volatile("s_waitcnt lgkmcnt(0)" ::: "memory");

    // PV + l accumulation (reads Vs[cur])
    const char* VsB = (const char*)Vs[cur];
    __builtin_amdgcn_s_setprio(1);
    #pragma unroll
    for (int ks2 = 0; ks2 < 2; ++ks2) {
      s16x8 pa = *(const s16x8*)(PsW + l15 * 128 + ((ks2 * 64 + g * 16) ^ swz));
      #pragma unroll
      for (int nd = 0; nd < 4; ++nd) {
        s16x8 vf = *(const s16x8*)(VsB + (nd * 16 + l15) * 128 + ((ks2 * 64 + g * 16) ^ swz));
        o[nd] = __builtin_amdgcn_mfma_f32_16x16x32_bf16(pa, vf, o[nd], 0, 0, 0);
      }
      ol = __builtin_amdgcn_mfma_f32_16x16x32_bf16(pa, ones, ol, 0, 0, 0);
    }
    __builtin_amdgcn_s_setprio(0);
    __syncthreads();                  // barrier B: K(t+1)/V(t+1) visible; V[cur] reads done
  }
#undef ALOADS
#undef STAGE_K
#undef STAGE_V

  #pragma unroll
  for (int nd = 0; nd < 4; ++nd) {
    #pragma unroll
    for (int r = 0; r < 4; ++r) {
      int q = q0 + g * 4 + r;
      int d = nd * 16 + l15;
      float val = o[nd][r] / ol[r];
      ctx[((size_t)(b * SQ + q)) * DM + h * HD + d] = f2bf(val);
    }
  }
}

// ---------------- output projection GEMM (BK=64): out = ctx @ Wo + bo (fp32) ----------------
__global__ __launch_bounds__(256) void out_gemm(
    const short* __restrict__ Actx, const short* __restrict__ Wot,
    const float* __restrict__ bo, float* __restrict__ out)
{
  __shared__ __align__(16) short As[128 * 64];
  __shared__ __align__(16) short Bs[128 * 64];
  int tid = threadIdx.x, lane = tid & 63, wid = tid >> 6;
  int bm = blockIdx.x >> 3, bn = blockIdx.x & 7;
  int m0 = bm * 128, n0 = bn * 128;

  int rs = tid >> 3;
  int cb8 = (tid & 7) * 8;
  int wr = wid >> 1, wc = wid & 1;
  int l15 = lane & 15, g = lane >> 4;

  f32x4 acc[4][4] = {};

  const short* gA = Actx + (size_t)(m0 + rs) * DM + cb8;
  const short* gB = Wot + (size_t)(n0 + rs) * DM + cb8;
  char* lA = (char*)As + tid * 16;
  char* lB = (char*)Bs + tid * 16;

  for (int kt = 0; kt < 16; ++kt) {
    int k0 = kt * 64;
    __syncthreads();
    GLOAD_LDS16(gA + k0,            lA);
    GLOAD_LDS16(gA + 32 * DM + k0,  lA + 4096);
    GLOAD_LDS16(gA + 64 * DM + k0,  lA + 8192);
    GLOAD_LDS16(gA + 96 * DM + k0,  lA + 12288);
    GLOAD_LDS16(gB + k0,            lB);
    GLOAD_LDS16(gB + 32 * DM + k0,  lB + 4096);
    GLOAD_LDS16(gB + 64 * DM + k0,  lB + 8192);
    GLOAD_LDS16(gB + 96 * DM + k0,  lB + 12288);
    __syncthreads();
    #pragma unroll
    for (int kk = 0; kk < 2; ++kk) {
      s16x8 af[4], bfr[4];
      #pragma unroll
      for (int mi = 0; mi < 4; ++mi)
        af[mi] = *(const s16x8*)((const char*)As + (wr * 64 + mi * 16 + l15) * 128 + kk * 64 + g * 16);
      #pragma unroll
      for (int ni = 0; ni < 4; ++ni)
        bfr[ni] = *(const s16x8*)((const char*)Bs + (wc * 64 + ni * 16 + l15) * 128 + kk * 64 + g * 16);
      #pragma unroll
      for (int mi = 0; mi < 4; ++mi)
        #pragma unroll
        for (int ni = 0; ni < 4; ++ni)
          acc[mi][ni] = __builtin_amdgcn_mfma_f32_16x16x32_bf16(af[mi], bfr[ni], acc[mi][ni], 0, 0, 0);
    }
  }

  #pragma unroll
  for (int mi = 0; mi < 4; ++mi) {
    #pragma unroll
    for (int ni = 0; ni < 4; ++ni) {
      int col = n0 + wc * 64 + ni * 16 + l15;
      float bb = bo[col];
      #pragma unroll
      for (int r = 0; r < 4; ++r) {
        int row = m0 + wr * 64 + mi * 16 + g * 4 + r;
        out[(size_t)row * DM + col] = acc[mi][ni][r] + bb;
      }
    }
  }
}

extern "C" void kernel_launch(void* const* d_in, const int* in_sizes, int n_in,
                              void* d_out, int out_size, void* d_ws, size_t ws_size,
                              hipStream_t stream) {
  const float* query = (const float*)d_in[0];
  const float* key   = (const float*)d_in[1];
  const float* value = (const float*)d_in[2];
  const int*   kmask = (const int*)d_in[3];
  const float* Wq = (const float*)d_in[4];
  const float* bq = (const float*)d_in[5];
  const float* Wk = (const float*)d_in[6];
  const float* bk = (const float*)d_in[7];
  const float* Wv = (const float*)d_in[8];
  const float* bv = (const float*)d_in[9];
  const float* Wo = (const float*)d_in[10];
  const float* bo = (const float*)d_in[11];
  float* out = (float*)d_out;

  char* ws = (char*)d_ws;
  short* Acat = (short*)ws;                       // 18432*1024 bf16 = 36 MB
  short* Wqt  = (short*)(ws + (size_t)37748736);  // 4 x 2MB
  short* Wkt  = Wqt + 1048576;
  short* Wvt  = Wkt + 1048576;
  short* Wot  = Wvt + 1048576;
  short* Qp   = Wot + 1048576;                    // [B,H,Sq,64]  4 MB
  short* Kp   = Qp + 2097152;                     // [B,H,Sk,64] 16 MB
  short* Vp   = Kp + 8388608;                     // [B,H,64,Sk] 16 MB
  short* ctx  = Vp + 8388608;                     // [B,Sq,1024]  4 MB
  uint32_t* mbits = (uint32_t*)(ctx + 2097152);   // 1 KB

  short* qbf = Acat;
  short* kbf = Acat + 2097152;
  short* vbf = Acat + 2097152 + 8388608;

  prep_kernel<<<2048, 256, 0, stream>>>(query, key, value, kmask, qbf, kbf, vbf, mbits);
  twall_kernel<<<1024, 256, 0, stream>>>(Wq, Wk, Wv, Wo, Wqt, Wkt, Wvt, Wot);
  proj_gemm<<<1152, 256, 0, stream>>>(Acat, Wqt, Wkt, Wvt, bq, bk, bv, Qp, Kp, Vp);
  attn_kernel<<<512, 256, 0, stream>>>(Qp, Kp, Vp, mbits, ctx);
  out_gemm<<<128, 256, 0, stream>>>(ctx, Wot, bo, out);
}

// Round 9
// 309.868 us; speedup vs baseline: 1.1526x; 1.0501x over previous
//
#include <hip/hip_runtime.h>
#include <stdint.h>

#define NH 16
#define HD 64
#define SQ 1024
#define SK 4096
#define DM 1024
#define MQ 2048      // B*Sq
#define MK 8192      // B*Sk
#define MTOT 18432   // MQ + MK + MK

typedef short s16x8 __attribute__((ext_vector_type(8)));
typedef short s16x4 __attribute__((ext_vector_type(4)));
typedef float f32x4 __attribute__((ext_vector_type(4)));

// async global->LDS DMA, 16B per lane; LDS dest must be wave-uniform-base + lane*16
#define GLOAD_LDS16(g, l) __builtin_amdgcn_global_load_lds( \
    (const __attribute__((address_space(1))) void*)(g), \
    (__attribute__((address_space(3))) void*)(l), 16, 0, 0)

__device__ __forceinline__ short f2bf(float f) {   // RNE
  union { float f; uint32_t u; } v; v.f = f;
  uint32_t r = (v.u + 0x7FFFu + ((v.u >> 16) & 1u)) >> 16;
  return (short)(uint16_t)r;
}
__device__ __forceinline__ short f2bf_rz(float f) { // truncate (P values >= 0)
  union { float f; uint32_t u; } v; v.f = f;
  return (short)(uint16_t)(v.u >> 16);
}

// ---------------- prep: fp32->bf16 for q/k/v + mask bitpack ----------------
__global__ void prep_kernel(const float* __restrict__ q, const float* __restrict__ k,
                            const float* __restrict__ v, const int* __restrict__ km,
                            short* __restrict__ qbf, short* __restrict__ kbf,
                            short* __restrict__ vbf, uint32_t* __restrict__ mbits) {
  int gid = blockIdx.x * 256 + threadIdx.x;
  if (gid < 256) {                         // 2*4096 mask bits -> 256 u32 words
    const int* kmw = km + gid * 32;
    uint32_t bits = 0;
    #pragma unroll
    for (int j = 0; j < 32; ++j) bits |= (kmw[j] ? 1u : 0u) << j;
    mbits[gid] = bits;
  }
  int stride = gridDim.x * 256;
  for (int i = gid; i < 2359296; i += stride) {   // total (2048+8192+8192)*1024/8
    const float* src; short* dst; int off;
    if (i < 262144)       { src = q; dst = qbf; off = i; }
    else if (i < 1310720) { src = k; dst = kbf; off = i - 262144; }
    else                  { src = v; dst = vbf; off = i - 1310720; }
    const float4* s4 = (const float4*)src + 2 * (size_t)off;
    float4 a = s4[0], b = s4[1];
    s16x8 o;
    o[0] = f2bf(a.x); o[1] = f2bf(a.y); o[2] = f2bf(a.z); o[3] = f2bf(a.w);
    o[4] = f2bf(b.x); o[5] = f2bf(b.y); o[6] = f2bf(b.z); o[7] = f2bf(b.w);
    *((s16x8*)dst + off) = o;
  }
}

// ---------------- weight transpose + convert, all 4 weights: W[K][N] f32 -> Wt[N][K] bf16 ----------------
__global__ void twall_kernel(const float* __restrict__ Wq, const float* __restrict__ Wk,
                             const float* __restrict__ Wv, const float* __restrict__ Wo,
                             short* __restrict__ Wqt, short* __restrict__ Wkt,
                             short* __restrict__ Wvt, short* __restrict__ Wot) {
  __shared__ __align__(16) short t[64][65];
  int wsel = blockIdx.x >> 8, bid = blockIdx.x & 255;
  const float* W = (wsel == 0) ? Wq : (wsel == 1) ? Wk : (wsel == 2) ? Wv : Wo;
  short* Wt = (wsel == 0) ? Wqt : (wsel == 1) ? Wkt : (wsel == 2) ? Wvt : Wot;
  int lx = threadIdx.x & 63, ly = threadIdx.x >> 6;
  int c0 = (bid & 15) * 64, r0 = (bid >> 4) * 64;
  #pragma unroll
  for (int i = ly; i < 64; i += 4) t[i][lx] = f2bf(W[(size_t)(r0 + i) * DM + c0 + lx]);
  __syncthreads();
  #pragma unroll
  for (int i = ly; i < 64; i += 4) Wt[(size_t)(c0 + i) * DM + r0 + lx] = t[lx][i];
}

// ---------------- fused QKV projection GEMM (BK=64, swizzled LDS) ----------------
// T2 fix per rule #21: gload_lds writes LINEAR; global SOURCE col is pre-swizzled
// (cb8 ^ ((row&7)<<3) elems); fragment READS apply byte ^ ((l15&7)<<4).
// Grid decode bm=bid%144, bn=bid/144: 144%8==0 -> each XCD owns a bm-residue class
// (A-panel locality: 4.5MB/XCD instead of 36MB).
__global__ __launch_bounds__(256) void proj_gemm(
    const short* __restrict__ Acat,
    const short* __restrict__ Wqt, const short* __restrict__ Wkt, const short* __restrict__ Wvt,
    const float* __restrict__ bq, const float* __restrict__ bk, const float* __restrict__ bv,
    short* __restrict__ Qp, short* __restrict__ Kp, short* __restrict__ Vp)
{
  __shared__ __align__(16) short As[128 * 64];
  __shared__ __align__(16) short Bs[128 * 64];
  int tid = threadIdx.x, lane = tid & 63, wid = tid >> 6;
  int bm = blockIdx.x % 144, bn = blockIdx.x / 144;
  int m0 = bm * 128, n0 = bn * 128;
  int seg = (m0 < MQ) ? 0 : (m0 < MQ + MK) ? 1 : 2;
  const short* Wt = (seg == 0) ? Wqt : (seg == 1) ? Wkt : Wvt;
  const float* bias = (seg == 0) ? bq : (seg == 1) ? bk : bv;

  int rs = tid >> 3;               // 0..31 (staging row)
  int cb8 = (tid & 7) * 8;         // staging k-col (elems)
  int scol = cb8 ^ ((rs & 7) << 3);  // pre-swizzled source col (elems)
  int wr = wid >> 1, wc = wid & 1;
  int l15 = lane & 15, g = lane >> 4;
  int swz = (l15 & 7) << 4;        // read-side swizzle (bytes)

  f32x4 acc[4][4] = {};

  const short* gA = Acat + (size_t)(m0 + rs) * DM + scol;
  const short* gB = Wt + (size_t)(n0 + rs) * DM + scol;
  char* lA = (char*)As + tid * 16;
  char* lB = (char*)Bs + tid * 16;

  for (int kt = 0; kt < 16; ++kt) {
    int k0 = kt * 64;
    __syncthreads();
    GLOAD_LDS16(gA + k0,            lA);
    GLOAD_LDS16(gA + 32 * DM + k0,  lA + 4096);
    GLOAD_LDS16(gA + 64 * DM + k0,  lA + 8192);
    GLOAD_LDS16(gA + 96 * DM + k0,  lA + 12288);
    GLOAD_LDS16(gB + k0,            lB);
    GLOAD_LDS16(gB + 32 * DM + k0,  lB + 4096);
    GLOAD_LDS16(gB + 64 * DM + k0,  lB + 8192);
    GLOAD_LDS16(gB + 96 * DM + k0,  lB + 12288);
    __syncthreads();
    #pragma unroll
    for (int kk = 0; kk < 2; ++kk) {
      s16x8 af[4], bfr[4];
      #pragma unroll
      for (int mi = 0; mi < 4; ++mi)
        af[mi] = *(const s16x8*)((const char*)As + (wr * 64 + mi * 16 + l15) * 128 + ((kk * 64 + g * 16) ^ swz));
      #pragma unroll
      for (int ni = 0; ni < 4; ++ni)
        bfr[ni] = *(const s16x8*)((const char*)Bs + (wc * 64 + ni * 16 + l15) * 128 + ((kk * 64 + g * 16) ^ swz));
      #pragma unroll
      for (int mi = 0; mi < 4; ++mi)
        #pragma unroll
        for (int ni = 0; ni < 4; ++ni)
          acc[mi][ni] = __builtin_amdgcn_mfma_f32_16x16x32_bf16(af[mi], bfr[ni], acc[mi][ni], 0, 0, 0);
    }
  }

  __syncthreads();   // epilogue reuses As as scratch

  if (seg == 2) {
    short* tw = (short*)As + wid * 288;   // [16][18] per wave
    int vbase = m0 - (MQ + MK) + wr * 64;
    #pragma unroll
    for (int mi = 0; mi < 4; ++mi) {
      int vr = vbase + mi * 16 + l15;
      int bb2 = vr >> 12, sk = vr & 4095;
      #pragma unroll
      for (int ni = 0; ni < 4; ++ni) {
        int col = n0 + wc * 64 + ni * 16;
        int h = col >> 6, d0 = col & 63;
        float bb = bias[col + l15];
        #pragma unroll
        for (int r = 0; r < 4; ++r)
          tw[(g * 4 + r) * 18 + l15] = f2bf(acc[mi][ni][r] + bb);
        #pragma unroll
        for (int j = 0; j < 4; ++j) {
          int dl = g * 4 + j;
          Vp[((size_t)(bb2 * NH + h) * HD + d0 + dl) * SK + sk] = tw[l15 * 18 + dl];
        }
      }
    }
  } else {
    // per-wave [16][64] shorts (2KB), XOR-swizzled; 16B coalesced global stores
    char* tw2 = (char*)As + wid * 2048;
    int hh = (n0 + wc * 64) >> 6;
    short* outp = (seg == 0) ? Qp : Kp;
    int sdim = (seg == 0) ? SQ : SK;
    int rbase = (seg == 0) ? m0 : m0 - MQ;
    int rmask = (seg == 0) ? 1023 : 4095;
    int rshift = (seg == 0) ? 10 : 12;
    #pragma unroll
    for (int mi = 0; mi < 4; ++mi) {
      #pragma unroll
      for (int ni = 0; ni < 4; ++ni) {
        float bb = bias[n0 + wc * 64 + ni * 16 + l15];
        #pragma unroll
        for (int r = 0; r < 4; ++r) {
          int rw = g * 4 + r;
          *(short*)(tw2 + rw * 128 + (((ni * 16 + l15) * 2) ^ ((rw & 7) << 4))) =
              f2bf(acc[mi][ni][r] + bb);
        }
      }
      asm volatile("s_waitcnt lgkmcnt(0)" ::: "memory");
      #pragma unroll
      for (int pp = 0; pp < 2; ++pp) {
        int lr = pp * 8 + (lane >> 3);
        int ce = (lane & 7) * 8;
        s16x8 v8 = *(const s16x8*)(tw2 + lr * 128 + ((ce * 2) ^ ((lr & 7) << 4)));
        int row = rbase + wr * 64 + mi * 16 + lr;
        int bI = row >> rshift, s = row & rmask;
        *(s16x8*)(outp + ((size_t)(bI * NH + hh) * sdim + s) * HD + ce) = v8;
      }
      asm volatile("s_waitcnt lgkmcnt(0)" ::: "memory");
    }
  }
}

// ---------------- flash attention (unchanged from round 8) ----------------
__global__ __launch_bounds__(256) void attn_kernel(
    const short* __restrict__ Qp, const short* __restrict__ Kp, const short* __restrict__ Vp,
    const uint32_t* __restrict__ mbits_g, short* __restrict__ ctx)
{
  __shared__ __align__(16) short Ks[64 * 64];      // [sk][d] swizzled, SINGLE buf (8KB)
  __shared__ __align__(16) short Vs[2][64 * 64];   // [d][sk] swizzled, dbuf (16KB)
  __shared__ __align__(16) short Ps[4][16 * 64];   // per-wave [q][k] swizzled (8KB)
  __shared__ uint32_t mb[128];                     // mask bits for this b (512B)

  int tid = threadIdx.x, lane = tid & 63, wid = tid >> 6;
  int bh = blockIdx.x & 31, qt = blockIdx.x >> 5;
  int b = bh >> 4, h = bh & 15;
  const short* Qb = Qp + (size_t)bh * SQ * HD;
  const short* Kb = Kp + (size_t)bh * SK * HD;
  const short* Vb = Vp + (size_t)bh * HD * SK;

  if (tid < 128) mb[tid] = mbits_g[b * 128 + tid];

  int l15 = lane & 15, g = lane >> 4, lh8 = g * 8;
  int q0 = qt * 64 + wid * 16;
  int swz = (l15 & 7) << 4;

  s16x8 aq[2];
  aq[0] = *(const s16x8*)(Qb + (size_t)(q0 + l15) * HD + lh8);
  aq[1] = *(const s16x8*)(Qb + (size_t)(q0 + l15) * HD + 32 + lh8);

  s16x8 ones;
  #pragma unroll
  for (int j = 0; j < 8; ++j) ones[j] = (short)0x3F80;  // bf16 1.0

  f32x4 o[4] = {};
  f32x4 ol = {};                      // row-sum (l) via ones-MFMA

  int srow = tid >> 3, scEl = (tid & 7) * 8;
  int wsoff = srow * 128 + ((scEl * 2) ^ ((srow & 7) << 4));  // swizzled byte offset

  s16x8 rk0, rk1, rv0, rv1;
#define ALOADS(t) { \
    rk0 = *(const s16x8*)(Kb + (size_t)((t) * 64 + srow) * HD + scEl); \
    rk1 = *(const s16x8*)(Kb + (size_t)((t) * 64 + srow + 32) * HD + scEl); \
    rv0 = *(const s16x8*)(Vb + (size_t)srow * SK + (t) * 64 + scEl); \
    rv1 = *(const s16x8*)(Vb + (size_t)(srow + 32) * SK + (t) * 64 + scEl); }
#define STAGE_K() { \
    *(s16x8*)((char*)Ks + wsoff) = rk0; *(s16x8*)((char*)Ks + wsoff + 4096) = rk1; }
#define STAGE_V(bi) { \
    char* vb_ = (char*)Vs[bi]; \
    *(s16x8*)(vb_ + wsoff) = rv0; *(s16x8*)(vb_ + wsoff + 4096) = rv1; }

  ALOADS(0); STAGE_K(); STAGE_V(0);
  ALOADS(1);
  __syncthreads();                    // K(0), V(0), mb visible

  const float sscale = 0.18033688f;   // 0.125 * log2(e)
  for (int t = 0; t < 64; ++t) {
    int cur = t & 1;
    if (t < 63) STAGE_V(cur ^ 1);     // V(t+1) -> other V buffer

    // S = Q K^T  (reads Ks)
    f32x4 sc[4] = {};
    __builtin_amdgcn_s_setprio(1);
    #pragma unroll
    for (int ni = 0; ni < 4; ++ni) {
      #pragma unroll
      for (int ks = 0; ks < 2; ++ks) {
        s16x8 kf = *(const s16x8*)((const char*)Ks + (ni * 16 + l15) * 128 + ((ks * 64 + g * 16) ^ swz));
        sc[ni] = __builtin_amdgcn_mfma_f32_16x16x32_bf16(aq[ks], kf, sc[ni], 0, 0, 0);
      }
    }
    __builtin_amdgcn_s_setprio(0);
    __syncthreads();                  // barrier A: all waves done reading Ks

    if (t < 63) STAGE_K();            // K(t+1) overwrites Ks, overlaps softmax/PV
    if (t < 62) ALOADS(t + 2);        // prefetch K/V(t+2)

    // P = exp2(S*sscale + ma), ma from bitmask: set -> -8 (shift), clear -> -1e9
    uint32_t w0 = mb[2 * t], w1 = mb[2 * t + 1];
    char* PsW = (char*)&Ps[wid][0];
    #pragma unroll
    for (int ni = 0; ni < 4; ++ni) {
      uint32_t w = (ni < 2) ? w0 : w1;
      float ma = ((w >> ((ni & 1) * 16 + l15)) & 1u) ? -8.0f : -1e9f;
      #pragma unroll
      for (int r = 0; r < 4; ++r) {
        float p = exp2f(sc[ni][r] * sscale + ma);
        int prow = g * 4 + r;
        *(short*)(PsW + prow * 128 + (((ni * 16 + l15) * 2) ^ ((prow & 7) << 4))) = f2bf_rz(p);
      }
    }
    asm volatile("s_waitcnt lgkmcnt(0)" ::: "memory");

    // PV + l accumulation (reads Vs[cur])
    const char* VsB = (const char*)Vs[cur];
    __builtin_amdgcn_s_setprio(1);
    #pragma unroll
    for (int ks2 = 0; ks2 < 2; ++ks2) {
      s16x8 pa = *(const s16x8*)(PsW + l15 * 128 + ((ks2 * 64 + g * 16) ^ swz));
      #pragma unroll
      for (int nd = 0; nd < 4; ++nd) {
        s16x8 vf = *(const s16x8*)(VsB + (nd * 16 + l15) * 128 + ((ks2 * 64 + g * 16) ^ swz));
        o[nd] = __builtin_amdgcn_mfma_f32_16x16x32_bf16(pa, vf, o[nd], 0, 0, 0);
      }
      ol = __builtin_amdgcn_mfma_f32_16x16x32_bf16(pa, ones, ol, 0, 0, 0);
    }
    __builtin_amdgcn_s_setprio(0);
    __syncthreads();                  // barrier B
  }
#undef ALOADS
#undef STAGE_K
#undef STAGE_V

  #pragma unroll
  for (int nd = 0; nd < 4; ++nd) {
    #pragma unroll
    for (int r = 0; r < 4; ++r) {
      int q = q0 + g * 4 + r;
      int d = nd * 16 + l15;
      float val = o[nd][r] / ol[r];
      ctx[((size_t)(b * SQ + q)) * DM + h * HD + d] = f2bf(val);
    }
  }
}

// ---------------- output projection GEMM (BK=64, swizzled LDS) ----------------
__global__ __launch_bounds__(256) void out_gemm(
    const short* __restrict__ Actx, const short* __restrict__ Wot,
    const float* __restrict__ bo, float* __restrict__ out)
{
  __shared__ __align__(16) short As[128 * 64];
  __shared__ __align__(16) short Bs[128 * 64];
  int tid = threadIdx.x, lane = tid & 63, wid = tid >> 6;
  int bm = blockIdx.x % 16, bn = blockIdx.x / 16;
  int m0 = bm * 128, n0 = bn * 128;

  int rs = tid >> 3;
  int cb8 = (tid & 7) * 8;
  int scol = cb8 ^ ((rs & 7) << 3);  // pre-swizzled source col (elems)
  int wr = wid >> 1, wc = wid & 1;
  int l15 = lane & 15, g = lane >> 4;
  int swz = (l15 & 7) << 4;

  f32x4 acc[4][4] = {};

  const short* gA = Actx + (size_t)(m0 + rs) * DM + scol;
  const short* gB = Wot + (size_t)(n0 + rs) * DM + scol;
  char* lA = (char*)As + tid * 16;
  char* lB = (char*)Bs + tid * 16;

  for (int kt = 0; kt < 16; ++kt) {
    int k0 = kt * 64;
    __syncthreads();
    GLOAD_LDS16(gA + k0,            lA);
    GLOAD_LDS16(gA + 32 * DM + k0,  lA + 4096);
    GLOAD_LDS16(gA + 64 * DM + k0,  lA + 8192);
    GLOAD_LDS16(gA + 96 * DM + k0,  lA + 12288);
    GLOAD_LDS16(gB + k0,            lB);
    GLOAD_LDS16(gB + 32 * DM + k0,  lB + 4096);
    GLOAD_LDS16(gB + 64 * DM + k0,  lB + 8192);
    GLOAD_LDS16(gB + 96 * DM + k0,  lB + 12288);
    __syncthreads();
    #pragma unroll
    for (int kk = 0; kk < 2; ++kk) {
      s16x8 af[4], bfr[4];
      #pragma unroll
      for (int mi = 0; mi < 4; ++mi)
        af[mi] = *(const s16x8*)((const char*)As + (wr * 64 + mi * 16 + l15) * 128 + ((kk * 64 + g * 16) ^ swz));
      #pragma unroll
      for (int ni = 0; ni < 4; ++ni)
        bfr[ni] = *(const s16x8*)((const char*)Bs + (wc * 64 + ni * 16 + l15) * 128 + ((kk * 64 + g * 16) ^ swz));
      #pragma unroll
      for (int mi = 0; mi < 4; ++mi)
        #pragma unroll
        for (int ni = 0; ni < 4; ++ni)
          acc[mi][ni] = __builtin_amdgcn_mfma_f32_16x16x32_bf16(af[mi], bfr[ni], acc[mi][ni], 0, 0, 0);
    }
  }

  #pragma unroll
  for (int mi = 0; mi < 4; ++mi) {
    #pragma unroll
    for (int ni = 0; ni < 4; ++ni) {
      int col = n0 + wc * 64 + ni * 16 + l15;
      float bb = bo[col];
      #pragma unroll
      for (int r = 0; r < 4; ++r) {
        int row = m0 + wr * 64 + mi * 16 + g * 4 + r;
        out[(size_t)row * DM + col] = acc[mi][ni][r] + bb;
      }
    }
  }
}

extern "C" void kernel_launch(void* const* d_in, const int* in_sizes, int n_in,
                              void* d_out, int out_size, void* d_ws, size_t ws_size,
                              hipStream_t stream) {
  const float* query = (const float*)d_in[0];
  const float* key   = (const float*)d_in[1];
  const float* value = (const float*)d_in[2];
  const int*   kmask = (const int*)d_in[3];
  const float* Wq = (const float*)d_in[4];
  const float* bq = (const float*)d_in[5];
  const float* Wk = (const float*)d_in[6];
  const float* bk = (const float*)d_in[7];
  const float* Wv = (const float*)d_in[8];
  const float* bv = (const float*)d_in[9];
  const float* Wo = (const float*)d_in[10];
  const float* bo = (const float*)d_in[11];
  float* out = (float*)d_out;

  char* ws = (char*)d_ws;
  short* Acat = (short*)ws;                       // 18432*1024 bf16 = 36 MB
  short* Wqt  = (short*)(ws + (size_t)37748736);  // 4 x 2MB
  short* Wkt  = Wqt + 1048576;
  short* Wvt  = Wkt + 1048576;
  short* Wot  = Wvt + 1048576;
  short* Qp   = Wot + 1048576;                    // [B,H,Sq,64]  4 MB
  short* Kp   = Qp + 2097152;                     // [B,H,Sk,64] 16 MB
  short* Vp   = Kp + 8388608;                     // [B,H,64,Sk] 16 MB
  short* ctx  = Vp + 8388608;                     // [B,Sq,1024]  4 MB
  uint32_t* mbits = (uint32_t*)(ctx + 2097152);   // 1 KB

  short* qbf = Acat;
  short* kbf = Acat + 2097152;
  short* vbf = Acat + 2097152 + 8388608;

  prep_kernel<<<2048, 256, 0, stream>>>(query, key, value, kmask, qbf, kbf, vbf, mbits);
  twall_kernel<<<1024, 256, 0, stream>>>(Wq, Wk, Wv, Wo, Wqt, Wkt, Wvt, Wot);
  proj_gemm<<<1152, 256, 0, stream>>>(Acat, Wqt, Wkt, Wvt, bq, bk, bv, Qp, Kp, Vp);
  attn_kernel<<<512, 256, 0, stream>>>(Qp, Kp, Vp, mbits, ctx);
  out_gemm<<<128, 256, 0, stream>>>(ctx, Wot, bo, out);
}